// Round 14
// baseline (266.810 us; speedup 1.0000x reference)
//
#include <hip/hip_runtime.h>

#define B_N 65536
#define K_SCALE 2.885390081777927f   // 2*log2(e): folded into W1-family & W2 weights

typedef __attribute__((ext_vector_type(8))) __bf16 bf16x8;
typedef __attribute__((ext_vector_type(8))) unsigned short ushort8;
typedef __attribute__((ext_vector_type(4))) float f32x4;
typedef __attribute__((ext_vector_type(4))) unsigned int uint32x4;

// ---------- ws layout (bytes) ----------
// 0..255  : 64 f32 per-block partial max|td| (plain stores; NO memset needed)
// 256     : WzT  bf16 [128][64]   sigma-z-permuted K, scaled by K_SCALE
// 16640   : W2T  bf16 [128][128]  sigma-permuted K,   scaled by K_SCALE
// 49408   : W3T  bf16 [64][128]   sigma-permuted K,   UNSCALED

__device__ __forceinline__ unsigned short f2bf(float f) {
    unsigned u = __float_as_uint(f);
    u += 0x7FFFu + ((u >> 16) & 1u);   // RNE
    return (unsigned short)(u >> 16);
}

// acc holds a = 2*log2e*x. tanh(x) = sign(a)*(1-w)/(1+w) with w = 2^(-|a|).
// ONE trans op (v_exp); the reciprocal of d=1+w in (1,2] is done on the FMA
// pipe: minimax linear seed r0 = 1.45711 - 0.5*d (rel err 0.086) + 2 Newton
// steps -> rel err 5.4e-5, far below the bf16 rounding (~4e-3) applied to h.
// Replaces exp+rcp (2 trans): the trans pipe was the hypothesized step wall.
// Saturates cleanly: |a| large -> w=0, d=1, r=1, y=1. No NaN paths. No LDS.
__device__ __forceinline__ float tanh_scaled(float a) {
    float w;
    asm("v_exp_f32 %0, %1" : "=v"(w) : "v"(-fabsf(a)));
    float d = w + 1.0f;
    float r = fmaf(-0.5f, w, 0.95711f);      // = 1.45711 - 0.5*d
    r = r * fmaf(-d, r, 2.0f);               // Newton 1
    r = r * fmaf(-d, r, 2.0f);               // Newton 2
    return __builtin_copysignf((1.0f - w) * r, a);
}

__device__ __forceinline__ unsigned cvt_pk_bf16(float lo, float hi) {
    unsigned r;
    asm("v_cvt_pk_bf16_f32 %0, %1, %2" : "=v"(r) : "v"(lo), "v"(hi));
    return r;
}

// K-index bit permutation: [kt][q:2][j2:1][j:2] -> [kt][j2:1][q:2][j:2].
// Baking sigma into the consumer weight's K order makes the producer MFMA's
// C-layout output (lane-local, col = lane&15 = own batch row) coincide
// EXACTLY with the consumer MFMA's B-fragment register layout.
__device__ __forceinline__ int sigma(int m) {
    return (m & 96) | ((m & 4) << 2) | ((m >> 1) & 12) | (m & 3);
}

// ---------- kernel 1: per-block td maxes (blocks 0..63) + prep (64..191) ----
// VERBATIM R11-verified version.
__global__ void k_pre(const float* __restrict__ td, const float* __restrict__ W1,
                      const float* __restrict__ W2, const float* __restrict__ W3,
                      float* __restrict__ ws) {
    if (blockIdx.x < 64) {
        __shared__ float red[4];
        float m = 0.0f;
        for (int i = blockIdx.x * 256 + threadIdx.x; i < B_N; i += 64 * 256)
            m = fmaxf(m, fabsf(td[i]));
#pragma unroll
        for (int o = 32; o; o >>= 1) m = fmaxf(m, __shfl_down(m, o));
        if ((threadIdx.x & 63) == 0) red[threadIdx.x >> 6] = m;
        __syncthreads();
        if (threadIdx.x == 0)
            ws[blockIdx.x] = fmaxf(fmaxf(red[0], red[1]), fmaxf(red[2], red[3]));
    } else {
        // 128 blocks * 256 threads = 32768 = exactly one bf16 element each
        int i = (blockIdx.x - 64) * 256 + threadIdx.x;
        unsigned short* wsb = (unsigned short*)((char*)ws + 256);
        float v;
        if (i < 8192) {                    // WzT[n][m] = K*W1[sigma(m)][n]
            int n = i >> 6, m = i & 63;
            v = W1[sigma(m) * 128 + n] * K_SCALE;
        } else if (i < 24576) {            // W2T[n][m] = K*W2[sigma(m)][n]
            int o = i - 8192;
            int n = o >> 7, m = o & 127;
            v = W2[sigma(m) * 128 + n] * K_SCALE;
        } else {                           // W3T[n][m] = W3[sigma(m)][n] (unscaled)
            int o = i - 24576;
            int n = o >> 7, m = o & 127;
            v = W3[sigma(m) * 64 + n];
        }
        wsb[i] = f2bf(v);
    }
}

// ---------- kernel 2: the ODE solver ----------
// 1 wave/SIMD, ALL weights in registers, ZERO LDS (empirical rule from 12
// runs: LDS + AGPR-backed weight hoist miscompiles; LDS-free passes 3/3).
// Step body = R11-verified dataflow; ONLY delta is the tanh internals.
__launch_bounds__(256, 1)
__global__ void k_main(const float* __restrict__ z_in, const float* __restrict__ td,
                       const float* __restrict__ W1, const float* __restrict__ b1,
                       const float* __restrict__ b2, const float* __restrict__ b3,
                       const void* __restrict__ ws, float* __restrict__ out) {
    const float* wsf = (const float*)ws;
    const unsigned short* wzg = (const unsigned short*)((const char*)ws + 256);
    const unsigned short* w2g = wzg + 8192;
    const unsigned short* w3g = wzg + 24576;

    const int tid = threadIdx.x;
    const int wave = tid >> 6;
    const int lane = tid & 63;
    const int q = lane >> 4;
    const int m15 = lane & 15;

    // ---- hoist ALL loop-invariant weights into registers ----
    bf16x8 wzf[8][2];   //  64 regs: Wz A-fragments (scaled)
    bf16x8 w2f[8][4];   // 128 regs: W2 A-fragments (scaled)
    bf16x8 w3f[4][4];   //  64 regs: W3 A-fragments (unscaled)
    bf16x8 augf[8];     //  32 regs: aug A-frag {pack(K*Wt, K*b1),0,0,0} on q==0
#pragma unroll
    for (int n0 = 0; n0 < 8; ++n0)
#pragma unroll
        for (int kt = 0; kt < 2; ++kt)
            wzf[n0][kt] = __builtin_bit_cast(
                bf16x8, *(const ushort8*)&wzg[(n0 * 16 + m15) * 64 + kt * 32 + q * 8]);
#pragma unroll
    for (int n0 = 0; n0 < 8; ++n0)
#pragma unroll
        for (int kt = 0; kt < 4; ++kt)
            w2f[n0][kt] = __builtin_bit_cast(
                bf16x8, *(const ushort8*)&w2g[(n0 * 16 + m15) * 128 + kt * 32 + q * 8]);
#pragma unroll
    for (int n0 = 0; n0 < 4; ++n0)
#pragma unroll
        for (int kt = 0; kt < 4; ++kt)
            w3f[n0][kt] = __builtin_bit_cast(
                bf16x8, *(const ushort8*)&w3g[(n0 * 16 + m15) * 128 + kt * 32 + q * 8]);
#pragma unroll
    for (int n0 = 0; n0 < 8; ++n0) {
        const int n = n0 * 16 + m15;
        float wt = W1[64 * 128 + n] * K_SCALE;   // Wt row of W1, scaled
        float bb = b1[n] * K_SCALE;
        unsigned w = (unsigned)f2bf(wt) | ((unsigned)f2bf(bb) << 16);
        w = (q == 0) ? w : 0u;                   // only k-slots 64,65 are live
        augf[n0] = __builtin_bit_cast(bf16x8, (uint32x4){w, 0u, 0u, 0u});
    }

    // b2 (scaled) rides in as the C-init of the first L2 MFMA
    f32x4 b2c[8];
#pragma unroll
    for (int n0 = 0; n0 < 8; ++n0) {
        f32x4 v = *(const f32x4*)&b2[n0 * 16 + q * 4];
#pragma unroll
        for (int r = 0; r < 4; ++r) v[r] *= K_SCALE;
        b2c[n0] = v;
    }

    // reduce the 64 per-block partial maxima (uniform, once per block)
    float maxab = 0.0f;
    for (int i = 0; i < 16; ++i) {
        f32x4 v = *(const f32x4*)&wsf[i * 4];
        maxab = fmaxf(maxab, fmaxf(fmaxf(v[0], v[1]), fmaxf(v[2], v[3])));
    }
    const int steps = (int)ceil((double)maxab / 0.1);   // matches np.ceil(float64)

    for (int tile = 0; tile < 4; ++tile) {
        const int row = blockIdx.x * 256 + tile * 64 + wave * 16 + m15;

        // zr[kt*8+hi*4+r] = z[row][kt*32 + hi*16 + q*4 + r]  (sigma_z baked in Wz)
        float zr[16];
#pragma unroll
        for (int kt = 0; kt < 2; ++kt)
#pragma unroll
            for (int hi = 0; hi < 2; ++hi) {
                f32x4 v = *(const f32x4*)(z_in + (size_t)row * 64 + kt * 32 + hi * 16 + q * 4);
#pragma unroll
                for (int r = 0; r < 4; ++r) zr[kt * 8 + hi * 4 + r] = v[r];
            }
        const float tdr = td[row];
        const float dtr = (steps > 0) ? (tdr / (float)steps) : 0.0f;

        for (int s = 0; s < steps; ++s) {
            const float t = (float)s * 0.1f;

            // ---- z -> bf16 B-fragments (8 cvt_pk) + t-augmentation word ----
            unsigned za[8];
#pragma unroll
            for (int i = 0; i < 8; ++i) za[i] = cvt_pk_bf16(zr[2 * i], zr[2 * i + 1]);
            unsigned tw = cvt_pk_bf16(t, 1.0f);
            tw = (q == 0) ? tw : 0u;
            bf16x8 zA0 = __builtin_bit_cast(bf16x8, (uint32x4){za[0], za[1], za[2], za[3]});
            bf16x8 zA1 = __builtin_bit_cast(bf16x8, (uint32x4){za[4], za[5], za[6], za[7]});
            bf16x8 zA2 = __builtin_bit_cast(bf16x8, (uint32x4){tw, 0u, 0u, 0u});

            // ---- layer 1: pre1 = K*(z@Wz + t*Wt + b1); h1 = tanh_scaled ----
            unsigned hv[16];
#pragma unroll
            for (int n0 = 0; n0 < 8; ++n0) {
                f32x4 acc = {0.f, 0.f, 0.f, 0.f};
                acc = __builtin_amdgcn_mfma_f32_16x16x32_bf16(wzf[n0][0], zA0, acc, 0, 0, 0);
                acc = __builtin_amdgcn_mfma_f32_16x16x32_bf16(wzf[n0][1], zA1, acc, 0, 0, 0);
                acc = __builtin_amdgcn_mfma_f32_16x16x32_bf16(augf[n0],   zA2, acc, 0, 0, 0);
                hv[n0 * 2 + 0] = cvt_pk_bf16(tanh_scaled(acc[0]), tanh_scaled(acc[1]));
                hv[n0 * 2 + 1] = cvt_pk_bf16(tanh_scaled(acc[2]), tanh_scaled(acc[3]));
            }

            // ---- layer 2: pre2 = K*(h1@W2 + b2) via scaled W2 + b2c C-init ----
            unsigned gv[16];
#pragma unroll
            for (int n0 = 0; n0 < 8; ++n0) {
                f32x4 acc = b2c[n0];
#pragma unroll
                for (int kt = 0; kt < 4; ++kt) {
                    bf16x8 hf = __builtin_bit_cast(
                        bf16x8, (uint32x4){hv[4 * kt], hv[4 * kt + 1],
                                           hv[4 * kt + 2], hv[4 * kt + 3]});
                    acc = __builtin_amdgcn_mfma_f32_16x16x32_bf16(w2f[n0][kt], hf, acc, 0, 0, 0);
                }
                gv[n0 * 2 + 0] = cvt_pk_bf16(tanh_scaled(acc[0]), tanh_scaled(acc[1]));
                gv[n0 * 2 + 1] = cvt_pk_bf16(tanh_scaled(acc[2]), tanh_scaled(acc[3]));
            }

            // ---- layer 3: dz = h2@W3 (unscaled); acc lands on zr[n0*4+r] ----
#pragma unroll
            for (int n0 = 0; n0 < 4; ++n0) {
                f32x4 acc = {0.f, 0.f, 0.f, 0.f};
#pragma unroll
                for (int kt = 0; kt < 4; ++kt) {
                    bf16x8 gf = __builtin_bit_cast(
                        bf16x8, (uint32x4){gv[4 * kt], gv[4 * kt + 1],
                                           gv[4 * kt + 2], gv[4 * kt + 3]});
                    acc = __builtin_amdgcn_mfma_f32_16x16x32_bf16(w3f[n0][kt], gf, acc, 0, 0, 0);
                }
#pragma unroll
                for (int r = 0; r < 4; ++r)
                    zr[n0 * 4 + r] = fmaf(acc[r], dtr, zr[n0 * 4 + r]);
            }
        }

        // b3 fold: sum_s dtr*b3 == td*b3 (exact linear fold, dz kept f32)
        const float tb3 = (steps > 0) ? tdr : 0.0f;
#pragma unroll
        for (int n0 = 0; n0 < 4; ++n0) {
            f32x4 bb = *(const f32x4*)&b3[n0 * 16 + q * 4];
#pragma unroll
            for (int r = 0; r < 4; ++r)
                zr[n0 * 4 + r] = fmaf(tb3, bb[r], zr[n0 * 4 + r]);
        }

        // store final z
#pragma unroll
        for (int kt = 0; kt < 2; ++kt)
#pragma unroll
            for (int hi = 0; hi < 2; ++hi) {
                f32x4 v;
#pragma unroll
                for (int r = 0; r < 4; ++r) v[r] = zr[kt * 8 + hi * 4 + r];
                *(f32x4*)(out + (size_t)row * 64 + kt * 32 + hi * 16 + q * 4) = v;
            }
    }
}

extern "C" void kernel_launch(void* const* d_in, const int* in_sizes, int n_in,
                              void* d_out, int out_size, void* d_ws, size_t ws_size,
                              hipStream_t stream) {
    const float* z  = (const float*)d_in[0];
    const float* td = (const float*)d_in[1];
    const float* W1 = (const float*)d_in[2];
    const float* b1 = (const float*)d_in[3];
    const float* W2 = (const float*)d_in[4];
    const float* b2 = (const float*)d_in[5];
    const float* W3 = (const float*)d_in[6];
    const float* b3 = (const float*)d_in[7];
    float* out = (float*)d_out;
    (void)in_sizes; (void)n_in; (void)out_size; (void)ws_size;

    k_pre<<<192, 256, 0, stream>>>(td, W1, W2, W3, (float*)d_ws);
    k_main<<<256, 256, 0, stream>>>(z, td, W1, b1, b2, b3, d_ws, out);
}

// Round 15
// 207.149 us; speedup vs baseline: 1.2880x; 1.2880x over previous
//
#include <hip/hip_runtime.h>

#define B_N 65536
#define K_SCALE 2.885390081777927f   // 2*log2(e): folded into W1-family & W2 weights

typedef __attribute__((ext_vector_type(8))) __bf16 bf16x8;
typedef __attribute__((ext_vector_type(8))) unsigned short ushort8;
typedef __attribute__((ext_vector_type(4))) float f32x4;
typedef __attribute__((ext_vector_type(4))) unsigned int uint32x4;

// ---------- ws layout (bytes) ----------
// 0..255  : 64 f32 per-block partial max|td| (plain stores; NO memset needed)
// 256     : WzT  bf16 [128][64]   sigma-z-permuted K, scaled by K_SCALE
// 16640   : W2T  bf16 [128][128]  sigma-permuted K,   scaled by K_SCALE
// 49408   : W3T  bf16 [64][128]   sigma-permuted K,   UNSCALED

__device__ __forceinline__ unsigned short f2bf(float f) {
    unsigned u = __float_as_uint(f);
    u += 0x7FFFu + ((u >> 16) & 1u);   // RNE
    return (unsigned short)(u >> 16);
}

// acc already holds 2*log2e*x: tanh(x) = 1 - 2/(2^acc + 1). Saturates cleanly.
// R14 measured: this 2-trans+2-VALU form beats a 1-trans+9-VALU Newton variant
// by 52% — the step is VALU-issue bound; trans ops are comparatively cheap.
__device__ __forceinline__ float tanh_scaled(float a) {
    float e;
    asm("v_exp_f32 %0, %1" : "=v"(e) : "v"(a));
    return fmaf(-2.0f, __builtin_amdgcn_rcpf(e + 1.0f), 1.0f);
}

__device__ __forceinline__ unsigned cvt_pk_bf16(float lo, float hi) {
    unsigned r;
    asm("v_cvt_pk_bf16_f32 %0, %1, %2" : "=v"(r) : "v"(lo), "v"(hi));
    return r;
}

// K-index bit permutation: [kt][q:2][j2:1][j:2] -> [kt][j2:1][q:2][j:2].
// Baking sigma into the consumer weight's K order makes the producer MFMA's
// C-layout output (lane-local, col = lane&15 = own batch row) coincide
// EXACTLY with the consumer MFMA's B-fragment register layout.
__device__ __forceinline__ int sigma(int m) {
    return (m & 96) | ((m & 4) << 2) | ((m >> 1) & 12) | (m & 3);
}

// ---------- kernel 1: per-block td maxes (blocks 0..63) + prep (64..191) ----
__global__ void k_pre(const float* __restrict__ td, const float* __restrict__ W1,
                      const float* __restrict__ W2, const float* __restrict__ W3,
                      float* __restrict__ ws) {
    if (blockIdx.x < 64) {
        __shared__ float red[4];
        float m = 0.0f;
        for (int i = blockIdx.x * 256 + threadIdx.x; i < B_N; i += 64 * 256)
            m = fmaxf(m, fabsf(td[i]));
#pragma unroll
        for (int o = 32; o; o >>= 1) m = fmaxf(m, __shfl_down(m, o));
        if ((threadIdx.x & 63) == 0) red[threadIdx.x >> 6] = m;
        __syncthreads();
        if (threadIdx.x == 0)
            ws[blockIdx.x] = fmaxf(fmaxf(red[0], red[1]), fmaxf(red[2], red[3]));
    } else {
        // 128 blocks * 256 threads = 32768 = exactly one bf16 element each
        int i = (blockIdx.x - 64) * 256 + threadIdx.x;
        unsigned short* wsb = (unsigned short*)((char*)ws + 256);
        float v;
        if (i < 8192) {                    // WzT[n][m] = K*W1[sigma(m)][n]
            int n = i >> 6, m = i & 63;
            v = W1[sigma(m) * 128 + n] * K_SCALE;
        } else if (i < 24576) {            // W2T[n][m] = K*W2[sigma(m)][n]
            int o = i - 8192;
            int n = o >> 7, m = o & 127;
            v = W2[sigma(m) * 128 + n] * K_SCALE;
        } else {                           // W3T[n][m] = W3[sigma(m)][n] (unscaled)
            int o = i - 24576;
            int n = o >> 7, m = o & 127;
            v = W3[sigma(m) * 64 + n];
        }
        wsb[i] = f2bf(v);
    }
}

// ---------- kernel 2: the ODE solver ----------
// 1 wave/SIMD (full 512-reg file per wave): ALL weights live in registers,
// the step loop has ZERO memory operations (no LDS, no global, no barriers).
// Empirical rule (12 runs): LDS in k_main + AGPR-backed weight hoist
// miscompiles; LDS-free passes consistently. block = 256 = 4 waves;
// grid = 256 = 1 block/CU; each wave runs 4 sequential 64-row tiles.
__launch_bounds__(256, 1)
__global__ void k_main(const float* __restrict__ z_in, const float* __restrict__ td,
                       const float* __restrict__ W1, const float* __restrict__ b1,
                       const float* __restrict__ b2, const float* __restrict__ b3,
                       const void* __restrict__ ws, float* __restrict__ out) {
    const float* wsf = (const float*)ws;
    const unsigned short* wzg = (const unsigned short*)((const char*)ws + 256);
    const unsigned short* w2g = wzg + 8192;
    const unsigned short* w3g = wzg + 24576;

    const int tid = threadIdx.x;
    const int wave = tid >> 6;
    const int lane = tid & 63;
    const int q = lane >> 4;
    const int m15 = lane & 15;

    // ---- hoist ALL loop-invariant weights into registers ----
    bf16x8 wzf[8][2];   //  64 regs: Wz A-fragments (scaled)
    bf16x8 w2f[8][4];   // 128 regs: W2 A-fragments (scaled)
    bf16x8 w3f[4][4];   //  64 regs: W3 A-fragments (unscaled)
    bf16x8 augf[8];     //  32 regs: aug A-frag {pack(K*Wt, K*b1),0,0,0} on q==0
#pragma unroll
    for (int n0 = 0; n0 < 8; ++n0)
#pragma unroll
        for (int kt = 0; kt < 2; ++kt)
            wzf[n0][kt] = __builtin_bit_cast(
                bf16x8, *(const ushort8*)&wzg[(n0 * 16 + m15) * 64 + kt * 32 + q * 8]);
#pragma unroll
    for (int n0 = 0; n0 < 8; ++n0)
#pragma unroll
        for (int kt = 0; kt < 4; ++kt)
            w2f[n0][kt] = __builtin_bit_cast(
                bf16x8, *(const ushort8*)&w2g[(n0 * 16 + m15) * 128 + kt * 32 + q * 8]);
#pragma unroll
    for (int n0 = 0; n0 < 4; ++n0)
#pragma unroll
        for (int kt = 0; kt < 4; ++kt)
            w3f[n0][kt] = __builtin_bit_cast(
                bf16x8, *(const ushort8*)&w3g[(n0 * 16 + m15) * 128 + kt * 32 + q * 8]);
#pragma unroll
    for (int n0 = 0; n0 < 8; ++n0) {
        const int n = n0 * 16 + m15;
        float wt = W1[64 * 128 + n] * K_SCALE;   // Wt row of W1, scaled
        float bb = b1[n] * K_SCALE;
        unsigned w = (unsigned)f2bf(wt) | ((unsigned)f2bf(bb) << 16);
        w = (q == 0) ? w : 0u;                   // only k-slots 64,65 are live
        augf[n0] = __builtin_bit_cast(bf16x8, (uint32x4){w, 0u, 0u, 0u});
    }

    // b2 (scaled) rides in as the C-init of the first L2 MFMA
    f32x4 b2c[8];
#pragma unroll
    for (int n0 = 0; n0 < 8; ++n0) {
        f32x4 v = *(const f32x4*)&b2[n0 * 16 + q * 4];
#pragma unroll
        for (int r = 0; r < 4; ++r) v[r] *= K_SCALE;
        b2c[n0] = v;
    }

    // reduce the 64 per-block partial maxima (uniform, once per block)
    float maxab = 0.0f;
    for (int i = 0; i < 16; ++i) {
        f32x4 v = *(const f32x4*)&wsf[i * 4];
        maxab = fmaxf(maxab, fmaxf(fmaxf(v[0], v[1]), fmaxf(v[2], v[3])));
    }
    const int steps = (int)ceil((double)maxab / 0.1);   // matches np.ceil(float64)

    for (int tile = 0; tile < 4; ++tile) {
        const int row = blockIdx.x * 256 + tile * 64 + wave * 16 + m15;

        // zr[kt*8+hi*4+r] = z[row][kt*32 + hi*16 + q*4 + r]  (sigma_z baked in Wz)
        float zr[16];
#pragma unroll
        for (int kt = 0; kt < 2; ++kt)
#pragma unroll
            for (int hi = 0; hi < 2; ++hi) {
                f32x4 v = *(const f32x4*)(z_in + (size_t)row * 64 + kt * 32 + hi * 16 + q * 4);
#pragma unroll
                for (int r = 0; r < 4; ++r) zr[kt * 8 + hi * 4 + r] = v[r];
            }
        const float tdr = td[row];
        const float dtr = (steps > 0) ? (tdr / (float)steps) : 0.0f;

        for (int s = 0; s < steps; ++s) {
            const float t = (float)s * 0.1f;

            // ---- z -> bf16 B-fragments (8 cvt_pk) + t-augmentation word ----
            unsigned za[8];
#pragma unroll
            for (int i = 0; i < 8; ++i) za[i] = cvt_pk_bf16(zr[2 * i], zr[2 * i + 1]);
            unsigned tw = cvt_pk_bf16(t, 1.0f);
            tw = (q == 0) ? tw : 0u;
            bf16x8 zA0 = __builtin_bit_cast(bf16x8, (uint32x4){za[0], za[1], za[2], za[3]});
            bf16x8 zA1 = __builtin_bit_cast(bf16x8, (uint32x4){za[4], za[5], za[6], za[7]});
            bf16x8 zA2 = __builtin_bit_cast(bf16x8, (uint32x4){tw, 0u, 0u, 0u});

            // ---- layer 1: pre1 = K*(z@Wz + t*Wt + b1); h1 = tanh_scaled ----
            unsigned hv[16];
#pragma unroll
            for (int n0 = 0; n0 < 8; ++n0) {
                f32x4 acc = {0.f, 0.f, 0.f, 0.f};
                acc = __builtin_amdgcn_mfma_f32_16x16x32_bf16(wzf[n0][0], zA0, acc, 0, 0, 0);
                acc = __builtin_amdgcn_mfma_f32_16x16x32_bf16(wzf[n0][1], zA1, acc, 0, 0, 0);
                acc = __builtin_amdgcn_mfma_f32_16x16x32_bf16(augf[n0],   zA2, acc, 0, 0, 0);
                hv[n0 * 2 + 0] = cvt_pk_bf16(tanh_scaled(acc[0]), tanh_scaled(acc[1]));
                hv[n0 * 2 + 1] = cvt_pk_bf16(tanh_scaled(acc[2]), tanh_scaled(acc[3]));
            }

            // ---- layer 2: pre2 = K*(h1@W2 + b2) via scaled W2 + b2c C-init ----
            unsigned gv[16];
#pragma unroll
            for (int n0 = 0; n0 < 8; ++n0) {
                f32x4 acc = b2c[n0];
#pragma unroll
                for (int kt = 0; kt < 4; ++kt) {
                    bf16x8 hf = __builtin_bit_cast(
                        bf16x8, (uint32x4){hv[4 * kt], hv[4 * kt + 1],
                                           hv[4 * kt + 2], hv[4 * kt + 3]});
                    acc = __builtin_amdgcn_mfma_f32_16x16x32_bf16(w2f[n0][kt], hf, acc, 0, 0, 0);
                }
                gv[n0 * 2 + 0] = cvt_pk_bf16(tanh_scaled(acc[0]), tanh_scaled(acc[1]));
                gv[n0 * 2 + 1] = cvt_pk_bf16(tanh_scaled(acc[2]), tanh_scaled(acc[3]));
            }

            // ---- layer 3: dz = h2@W3 (unscaled); acc lands on zr[n0*4+r] ----
#pragma unroll
            for (int n0 = 0; n0 < 4; ++n0) {
                f32x4 acc = {0.f, 0.f, 0.f, 0.f};
#pragma unroll
                for (int kt = 0; kt < 4; ++kt) {
                    bf16x8 gf = __builtin_bit_cast(
                        bf16x8, (uint32x4){gv[4 * kt], gv[4 * kt + 1],
                                           gv[4 * kt + 2], gv[4 * kt + 3]});
                    acc = __builtin_amdgcn_mfma_f32_16x16x32_bf16(w3f[n0][kt], gf, acc, 0, 0, 0);
                }
#pragma unroll
                for (int r = 0; r < 4; ++r)
                    zr[n0 * 4 + r] = fmaf(acc[r], dtr, zr[n0 * 4 + r]);
            }
        }

        // b3 fold: sum_s dtr*b3 == td*b3 (exact linear fold, dz kept f32)
        const float tb3 = (steps > 0) ? tdr : 0.0f;
#pragma unroll
        for (int n0 = 0; n0 < 4; ++n0) {
            f32x4 bb = *(const f32x4*)&b3[n0 * 16 + q * 4];
#pragma unroll
            for (int r = 0; r < 4; ++r)
                zr[n0 * 4 + r] = fmaf(tb3, bb[r], zr[n0 * 4 + r]);
        }

        // store final z
#pragma unroll
        for (int kt = 0; kt < 2; ++kt)
#pragma unroll
            for (int hi = 0; hi < 2; ++hi) {
                f32x4 v;
#pragma unroll
                for (int r = 0; r < 4; ++r) v[r] = zr[kt * 8 + hi * 4 + r];
                *(f32x4*)(out + (size_t)row * 64 + kt * 32 + hi * 16 + q * 4) = v;
            }
    }
}

extern "C" void kernel_launch(void* const* d_in, const int* in_sizes, int n_in,
                              void* d_out, int out_size, void* d_ws, size_t ws_size,
                              hipStream_t stream) {
    const float* z  = (const float*)d_in[0];
    const float* td = (const float*)d_in[1];
    const float* W1 = (const float*)d_in[2];
    const float* b1 = (const float*)d_in[3];
    const float* W2 = (const float*)d_in[4];
    const float* b2 = (const float*)d_in[5];
    const float* W3 = (const float*)d_in[6];
    const float* b3 = (const float*)d_in[7];
    float* out = (float*)d_out;
    (void)in_sizes; (void)n_in; (void)out_size; (void)ws_size;

    k_pre<<<192, 256, 0, stream>>>(td, W1, W2, W3, (float*)d_ws);
    k_main<<<256, 256, 0, stream>>>(z, td, W1, b1, b2, b3, d_ws, out);
}